// Round 1
// baseline (200.263 us; speedup 1.0000x reference)
//
#include <hip/hip_runtime.h>
#include <math.h>

#define GAMMA_F 0.2f
#define NTHREADS 256
#define TILE 2048
#define NSPLIT 16

__device__ __forceinline__ float sigmoid_from_logits(float y0, float y1) {
    // softmax[:,1] = 1 / (1 + exp(y0 - y1))
    return 1.0f / (1.0f + __expf(y0 - y1));
}

__device__ __forceinline__ void block_reduce_and_atomic(float acc, float* out) {
    // wave (64-lane) shuffle reduce, then cross-wave via LDS, one atomic per block
    #pragma unroll
    for (int off = 32; off > 0; off >>= 1) acc += __shfl_down(acc, off, 64);
    __shared__ float wsum[NTHREADS / 64];
    int tid = threadIdx.x;
    int wave = tid >> 6, lane = tid & 63;
    if (lane == 0) wsum[wave] = acc;
    __syncthreads();
    if (tid == 0) {
        float s = 0.0f;
        #pragma unroll
        for (int w = 0; w < NTHREADS / 64; ++w) s += wsum[w];
        atomicAdd(out, s);
    }
}

// Kernel A: compute s_i, partition into pos/neg arrays via atomic compaction.
__global__ void compact_kernel(const float* __restrict__ y_pred,
                               const int* __restrict__ y_true,
                               int n, int* __restrict__ counters,
                               float* __restrict__ pos_arr,
                               float* __restrict__ neg_arr) {
    int i = blockIdx.x * blockDim.x + threadIdx.x;
    if (i >= n) return;
    float y0 = y_pred[2 * i];
    float y1 = y_pred[2 * i + 1];
    float s = sigmoid_from_logits(y0, y1);
    if (y_true[i] == 1) {
        int k = atomicAdd(&counters[0], 1);
        pos_arr[k] = s;
    } else {
        int k = atomicAdd(&counters[1], 1);
        neg_arr[k] = s;
    }
}

// Kernel B: each thread owns one positive; blocks stage negative tiles in LDS.
__global__ __launch_bounds__(NTHREADS) void pair_kernel(
        const int* __restrict__ counters,
        const float* __restrict__ pos_arr,
        const float* __restrict__ neg_arr,
        float* __restrict__ out) {
    __shared__ float lds[TILE];
    int n_pos = counters[0];
    int n_neg = counters[1];
    int base = blockIdx.x * NTHREADS;
    if (base >= n_pos) return;  // uniform early exit (before any barrier)
    int tid = threadIdx.x;
    int i = base + tid;
    // inactive lanes get a huge a' so every contribution clamps to 0
    float aShift = (i < n_pos) ? (pos_arr[i] - GAMMA_F) : 1e30f;

    int len = (n_neg + NSPLIT - 1) / NSPLIT;
    int j0 = blockIdx.y * len;
    int j1 = min(n_neg, j0 + len);

    float acc0 = 0.0f, acc1 = 0.0f, acc2 = 0.0f, acc3 = 0.0f;
    for (int t0 = j0; t0 < j1; t0 += TILE) {
        int cnt = min(TILE, j1 - t0);
        __syncthreads();
        for (int k = tid; k < cnt; k += NTHREADS) lds[k] = neg_arr[t0 + k];
        __syncthreads();
        int cnt4 = cnt & ~3;
        const float4* lds4 = (const float4*)lds;
        for (int k4 = 0; k4 < (cnt4 >> 2); ++k4) {
            float4 b = lds4[k4];
            float t0f = fmaxf(b.x - aShift, 0.0f);
            float t1f = fmaxf(b.y - aShift, 0.0f);
            float t2f = fmaxf(b.z - aShift, 0.0f);
            float t3f = fmaxf(b.w - aShift, 0.0f);
            acc0 += t0f * t0f * t0f;
            acc1 += t1f * t1f * t1f;
            acc2 += t2f * t2f * t2f;
            acc3 += t3f * t3f * t3f;
        }
        for (int k = cnt4; k < cnt; ++k) {
            float t = fmaxf(lds[k] - aShift, 0.0f);
            acc0 += t * t * t;
        }
    }
    block_reduce_and_atomic((acc0 + acc1) + (acc2 + acc3), out);
}

// Fallback (if workspace too small): fused masked pairwise over raw inputs.
__global__ __launch_bounds__(NTHREADS) void fused_kernel(
        const float* __restrict__ y_pred, const int* __restrict__ y_true,
        int n, float* __restrict__ out) {
    __shared__ float lds[TILE];
    int tid = threadIdx.x;
    int i = blockIdx.x * NTHREADS + tid;
    float aShift = 1e30f;  // non-positive rows contribute 0
    if (i < n && y_true[i] == 1)
        aShift = sigmoid_from_logits(y_pred[2 * i], y_pred[2 * i + 1]) - GAMMA_F;

    int len = (n + NSPLIT - 1) / NSPLIT;
    int j0 = blockIdx.y * len;
    int j1 = min(n, j0 + len);

    float acc0 = 0.0f, acc1 = 0.0f, acc2 = 0.0f, acc3 = 0.0f;
    for (int t0 = j0; t0 < j1; t0 += TILE) {
        int cnt = min(TILE, j1 - t0);
        __syncthreads();
        for (int k = tid; k < cnt; k += NTHREADS) {
            int j = t0 + k;
            float b = -1e30f;  // positive columns as "negatives" contribute 0
            if (y_true[j] != 1)
                b = sigmoid_from_logits(y_pred[2 * j], y_pred[2 * j + 1]);
            lds[k] = b;
        }
        __syncthreads();
        int cnt4 = cnt & ~3;
        const float4* lds4 = (const float4*)lds;
        for (int k4 = 0; k4 < (cnt4 >> 2); ++k4) {
            float4 b = lds4[k4];
            float t0f = fmaxf(b.x - aShift, 0.0f);
            float t1f = fmaxf(b.y - aShift, 0.0f);
            float t2f = fmaxf(b.z - aShift, 0.0f);
            float t3f = fmaxf(b.w - aShift, 0.0f);
            acc0 += t0f * t0f * t0f;
            acc1 += t1f * t1f * t1f;
            acc2 += t2f * t2f * t2f;
            acc3 += t3f * t3f * t3f;
        }
        for (int k = cnt4; k < cnt; ++k) {
            float t = fmaxf(lds[k] - aShift, 0.0f);
            acc0 += t * t * t;
        }
    }
    block_reduce_and_atomic((acc0 + acc1) + (acc2 + acc3), out);
}

extern "C" void kernel_launch(void* const* d_in, const int* in_sizes, int n_in,
                              void* d_out, int out_size, void* d_ws, size_t ws_size,
                              hipStream_t stream) {
    const float* y_pred = (const float*)d_in[0];
    const int* y_true = (const int*)d_in[1];
    int n = in_sizes[1];  // N (y_true element count); y_pred has 2N
    float* out = (float*)d_out;

    // d_out / d_ws are re-poisoned to 0xAA before every launch — zero what we use.
    hipMemsetAsync(d_out, 0, sizeof(float), stream);

    size_t need = 16 * sizeof(int) + 2 * (size_t)n * sizeof(float);
    if (ws_size >= need) {
        int* counters = (int*)d_ws;
        float* pos_arr = (float*)d_ws + 16;
        float* neg_arr = pos_arr + n;
        hipMemsetAsync(d_ws, 0, 2 * sizeof(int), stream);
        int grid_a = (n + NTHREADS - 1) / NTHREADS;
        compact_kernel<<<grid_a, NTHREADS, 0, stream>>>(y_pred, y_true, n,
                                                        counters, pos_arr, neg_arr);
        dim3 grid_b((n + NTHREADS - 1) / NTHREADS, NSPLIT);
        pair_kernel<<<grid_b, NTHREADS, 0, stream>>>(counters, pos_arr, neg_arr, out);
    } else {
        dim3 grid((n + NTHREADS - 1) / NTHREADS, NSPLIT);
        fused_kernel<<<grid, NTHREADS, 0, stream>>>(y_pred, y_true, n, out);
    }
}

// Round 2
// 79.320 us; speedup vs baseline: 2.5247x; 2.5247x over previous
//
#include <hip/hip_runtime.h>
#include <math.h>

#define GAMMA_F 0.2f
#define NTHREADS 256
#define TILE 2048
#define NSPLIT 16

__device__ __forceinline__ float sigmoid_from_logits(float y0, float y1) {
    // softmax[:,1] = 1 / (1 + exp(y0 - y1))
    return 1.0f / (1.0f + __expf(y0 - y1));
}

__device__ __forceinline__ void block_reduce_and_atomic(float acc, float* out) {
    // wave (64-lane) shuffle reduce, then cross-wave via LDS, one atomic per block
    #pragma unroll
    for (int off = 32; off > 0; off >>= 1) acc += __shfl_down(acc, off, 64);
    __shared__ float wsum[NTHREADS / 64];
    int tid = threadIdx.x;
    int wave = tid >> 6, lane = tid & 63;
    if (lane == 0) wsum[wave] = acc;
    __syncthreads();
    if (tid == 0) {
        float s = 0.0f;
        #pragma unroll
        for (int w = 0; w < NTHREADS / 64; ++w) s += wsum[w];
        atomicAdd(out, s);
    }
}

// Kernel A: compute s_i, partition into pos/neg arrays.
// Wave-aggregated compaction: ONE atomic per class per wave (not per thread) —
// per-thread atomicAdd-with-return to 2 addresses serialized at ~19 cyc each
// (measured 128 us for 16384 atomics in R1).
__global__ void compact_kernel(const float* __restrict__ y_pred,
                               const int* __restrict__ y_true,
                               int n, int* __restrict__ counters,
                               float* __restrict__ pos_arr,
                               float* __restrict__ neg_arr) {
    int i = blockIdx.x * blockDim.x + threadIdx.x;
    bool valid = (i < n);
    bool is_pos = false;
    float s = 0.0f;
    if (valid) {
        float2 y = ((const float2*)y_pred)[i];  // coalesced 8B/lane
        s = sigmoid_from_logits(y.x, y.y);
        is_pos = (y_true[i] == 1);
    }
    unsigned long long mpos = __ballot(valid && is_pos);
    unsigned long long mneg = __ballot(valid && !is_pos);
    int lane = threadIdx.x & 63;
    unsigned long long lt = (1ULL << lane) - 1ULL;
    int base_pos = 0, base_neg = 0;
    if (lane == 0) {
        base_pos = atomicAdd(&counters[0], __popcll(mpos));
        base_neg = atomicAdd(&counters[1], __popcll(mneg));
    }
    base_pos = __shfl(base_pos, 0, 64);
    base_neg = __shfl(base_neg, 0, 64);
    if (valid) {
        if (is_pos) pos_arr[base_pos + __popcll(mpos & lt)] = s;
        else        neg_arr[base_neg + __popcll(mneg & lt)] = s;
    }
}

// Kernel B: each thread owns one positive; blocks stage negative tiles in LDS.
__global__ __launch_bounds__(NTHREADS) void pair_kernel(
        const int* __restrict__ counters,
        const float* __restrict__ pos_arr,
        const float* __restrict__ neg_arr,
        float* __restrict__ out) {
    __shared__ float lds[TILE];
    int n_pos = counters[0];
    int n_neg = counters[1];
    int base = blockIdx.x * NTHREADS;
    if (base >= n_pos) return;  // uniform early exit (before any barrier)
    int tid = threadIdx.x;
    int i = base + tid;
    // inactive lanes get a huge a' so every contribution clamps to 0
    float aShift = (i < n_pos) ? (pos_arr[i] - GAMMA_F) : 1e30f;

    int len = (n_neg + NSPLIT - 1) / NSPLIT;
    int j0 = blockIdx.y * len;
    int j1 = min(n_neg, j0 + len);

    float acc0 = 0.0f, acc1 = 0.0f, acc2 = 0.0f, acc3 = 0.0f;
    for (int t0 = j0; t0 < j1; t0 += TILE) {
        int cnt = min(TILE, j1 - t0);
        __syncthreads();
        for (int k = tid; k < cnt; k += NTHREADS) lds[k] = neg_arr[t0 + k];
        __syncthreads();
        int cnt4 = cnt & ~3;
        const float4* lds4 = (const float4*)lds;
        for (int k4 = 0; k4 < (cnt4 >> 2); ++k4) {
            float4 b = lds4[k4];
            float t0f = fmaxf(b.x - aShift, 0.0f);
            float t1f = fmaxf(b.y - aShift, 0.0f);
            float t2f = fmaxf(b.z - aShift, 0.0f);
            float t3f = fmaxf(b.w - aShift, 0.0f);
            acc0 += t0f * t0f * t0f;
            acc1 += t1f * t1f * t1f;
            acc2 += t2f * t2f * t2f;
            acc3 += t3f * t3f * t3f;
        }
        for (int k = cnt4; k < cnt; ++k) {
            float t = fmaxf(lds[k] - aShift, 0.0f);
            acc0 += t * t * t;
        }
    }
    block_reduce_and_atomic((acc0 + acc1) + (acc2 + acc3), out);
}

// Fallback (if workspace too small): fused masked pairwise over raw inputs.
__global__ __launch_bounds__(NTHREADS) void fused_kernel(
        const float* __restrict__ y_pred, const int* __restrict__ y_true,
        int n, float* __restrict__ out) {
    __shared__ float lds[TILE];
    int tid = threadIdx.x;
    int i = blockIdx.x * NTHREADS + tid;
    float aShift = 1e30f;  // non-positive rows contribute 0
    if (i < n && y_true[i] == 1)
        aShift = sigmoid_from_logits(y_pred[2 * i], y_pred[2 * i + 1]) - GAMMA_F;

    int len = (n + NSPLIT - 1) / NSPLIT;
    int j0 = blockIdx.y * len;
    int j1 = min(n, j0 + len);

    float acc0 = 0.0f, acc1 = 0.0f, acc2 = 0.0f, acc3 = 0.0f;
    for (int t0 = j0; t0 < j1; t0 += TILE) {
        int cnt = min(TILE, j1 - t0);
        __syncthreads();
        for (int k = tid; k < cnt; k += NTHREADS) {
            int j = t0 + k;
            float b = -1e30f;  // positive columns as "negatives" contribute 0
            if (y_true[j] != 1)
                b = sigmoid_from_logits(y_pred[2 * j], y_pred[2 * j + 1]);
            lds[k] = b;
        }
        __syncthreads();
        int cnt4 = cnt & ~3;
        const float4* lds4 = (const float4*)lds;
        for (int k4 = 0; k4 < (cnt4 >> 2); ++k4) {
            float4 b = lds4[k4];
            float t0f = fmaxf(b.x - aShift, 0.0f);
            float t1f = fmaxf(b.y - aShift, 0.0f);
            float t2f = fmaxf(b.z - aShift, 0.0f);
            float t3f = fmaxf(b.w - aShift, 0.0f);
            acc0 += t0f * t0f * t0f;
            acc1 += t1f * t1f * t1f;
            acc2 += t2f * t2f * t2f;
            acc3 += t3f * t3f * t3f;
        }
        for (int k = cnt4; k < cnt; ++k) {
            float t = fmaxf(lds[k] - aShift, 0.0f);
            acc0 += t * t * t;
        }
    }
    block_reduce_and_atomic((acc0 + acc1) + (acc2 + acc3), out);
}

extern "C" void kernel_launch(void* const* d_in, const int* in_sizes, int n_in,
                              void* d_out, int out_size, void* d_ws, size_t ws_size,
                              hipStream_t stream) {
    const float* y_pred = (const float*)d_in[0];
    const int* y_true = (const int*)d_in[1];
    int n = in_sizes[1];  // N (y_true element count); y_pred has 2N
    float* out = (float*)d_out;

    // d_out / d_ws are re-poisoned to 0xAA before every launch — zero what we use.
    hipMemsetAsync(d_out, 0, sizeof(float), stream);

    size_t need = 16 * sizeof(int) + 2 * (size_t)n * sizeof(float);
    if (ws_size >= need) {
        int* counters = (int*)d_ws;
        float* pos_arr = (float*)d_ws + 16;
        float* neg_arr = pos_arr + n;
        hipMemsetAsync(d_ws, 0, 2 * sizeof(int), stream);
        int grid_a = (n + NTHREADS - 1) / NTHREADS;
        compact_kernel<<<grid_a, NTHREADS, 0, stream>>>(y_pred, y_true, n,
                                                        counters, pos_arr, neg_arr);
        dim3 grid_b((n + NTHREADS - 1) / NTHREADS, NSPLIT);
        pair_kernel<<<grid_b, NTHREADS, 0, stream>>>(counters, pos_arr, neg_arr, out);
    } else {
        dim3 grid((n + NTHREADS - 1) / NTHREADS, NSPLIT);
        fused_kernel<<<grid, NTHREADS, 0, stream>>>(y_pred, y_true, n, out);
    }
}

// Round 3
// 70.729 us; speedup vs baseline: 2.8314x; 1.1215x over previous
//
#include <hip/hip_runtime.h>
#include <math.h>

#define GAMMA_F 0.2f
#define NT 256
#define MAXLEN 1024  // max columns per block.y slice

__device__ __forceinline__ float sigmoid_from_logits(float y0, float y1) {
    // softmax[:,1] = 1 / (1 + exp(y0 - y1))
    return 1.0f / (1.0f + __expf(y0 - y1));
}

// Single fused kernel: per-block LDS compaction of rows (positives) and a
// column slice (negatives), then the pair hinge^3 loop. One plain-store
// partial per block into d_ws (overwrites 0xAA poison — no memset needed).
__global__ __launch_bounds__(NT) void fused_pair_kernel(
        const float* __restrict__ y_pred, const int* __restrict__ y_true,
        int n, int len, float* __restrict__ partials) {
    __shared__ float row_a[NT];         // compacted pos scores - gamma
    __shared__ float col_s[MAXLEN + 4]; // compacted neg scores
    __shared__ int cnts[2];             // [0]=n_rows(pos), [1]=n_cols(neg)
    __shared__ float wsum[NT / 64];

    int tid = threadIdx.x;
    int lane = tid & 63;
    unsigned long long lt = (1ULL << lane) - 1ULL;
    if (tid < 2) cnts[tid] = 0;
    __syncthreads();

    // ---- row compaction: this block's 256 original rows, keep positives ----
    {
        int i = blockIdx.x * NT + tid;
        bool in = (i < n);
        float a = 0.0f;
        bool is_pos = false;
        if (in) {
            float2 y = ((const float2*)y_pred)[i];  // coalesced 8B/lane
            a = sigmoid_from_logits(y.x, y.y) - GAMMA_F;
            is_pos = (y_true[i] == 1);
        }
        unsigned long long m = __ballot(is_pos);
        int base = 0;
        if (lane == 0) base = atomicAdd(&cnts[0], __popcll(m));
        base = __shfl(base, 0, 64);
        if (is_pos) row_a[base + __popcll(m & lt)] = a;
    }

    // ---- column compaction: slice [j0, j1), keep negatives ----
    int j0 = blockIdx.y * len;
    int j1 = min(n, j0 + len);
    for (int c = j0; c < j1; c += NT) {  // wave-uniform trip count
        int j = c + tid;
        bool in = (j < j1);
        float s = 0.0f;
        bool is_neg = false;
        if (in) {
            float2 y = ((const float2*)y_pred)[j];
            s = sigmoid_from_logits(y.x, y.y);
            is_neg = (y_true[j] != 1);
        }
        unsigned long long m = __ballot(is_neg);
        int base = 0;
        if (lane == 0) base = atomicAdd(&cnts[1], __popcll(m));
        base = __shfl(base, 0, 64);
        if (is_neg) col_s[base + __popcll(m & lt)] = s;
    }
    __syncthreads();

    int n_rows = cnts[0];
    int n_cols = cnts[1];

    // ---- pair loop: 2 threads per row, columns split in (aligned) halves ----
    int half = (n_cols / 2) & ~3;  // keep float4 alignment for both halves
    int p = tid & 1;
    int c0 = p ? half : 0;
    int c1 = p ? n_cols : half;
    int c4len = (c1 - c0) & ~3;

    float acc0 = 0.0f, acc1 = 0.0f, acc2 = 0.0f, acc3 = 0.0f;
    for (int r = tid >> 1; r < n_rows; r += NT / 2) {
        float av = row_a[r];
        int c = c0;
        int c4end = c0 + c4len;
        for (; c < c4end; c += 4) {
            float4 b = *(const float4*)&col_s[c];  // 2 uniform addrs/wave -> broadcast
            float t0 = fmaxf(b.x - av, 0.0f);
            float t1 = fmaxf(b.y - av, 0.0f);
            float t2 = fmaxf(b.z - av, 0.0f);
            float t3 = fmaxf(b.w - av, 0.0f);
            acc0 += (t0 * t0) * t0;
            acc1 += (t1 * t1) * t1;
            acc2 += (t2 * t2) * t2;
            acc3 += (t3 * t3) * t3;
        }
        for (; c < c1; ++c) {
            float t = fmaxf(col_s[c] - av, 0.0f);
            acc0 += (t * t) * t;
        }
    }
    float acc = (acc0 + acc1) + (acc2 + acc3);

    // ---- block reduce -> one plain store per block ----
    #pragma unroll
    for (int off = 32; off > 0; off >>= 1) acc += __shfl_down(acc, off, 64);
    int wave = tid >> 6;
    if (lane == 0) wsum[wave] = acc;
    __syncthreads();
    if (tid == 0) {
        float s = 0.0f;
        #pragma unroll
        for (int w = 0; w < NT / 64; ++w) s += wsum[w];
        partials[blockIdx.y * gridDim.x + blockIdx.x] = s;
    }
}

// Deterministic tree-reduce of the per-block partials; plain store to d_out.
__global__ __launch_bounds__(NT) void reduce_kernel(
        const float* __restrict__ partials, int nb, float* __restrict__ out) {
    int tid = threadIdx.x;
    float s = 0.0f;
    for (int k = tid; k < nb; k += NT) s += partials[k];
    #pragma unroll
    for (int off = 32; off > 0; off >>= 1) s += __shfl_down(s, off, 64);
    __shared__ float wsum[NT / 64];
    int wave = tid >> 6, lane = tid & 63;
    if (lane == 0) wsum[wave] = s;
    __syncthreads();
    if (tid == 0) {
        float t = 0.0f;
        #pragma unroll
        for (int w = 0; w < NT / 64; ++w) t += wsum[w];
        out[0] = t;
    }
}

extern "C" void kernel_launch(void* const* d_in, const int* in_sizes, int n_in,
                              void* d_out, int out_size, void* d_ws, size_t ws_size,
                              hipStream_t stream) {
    const float* y_pred = (const float*)d_in[0];
    const int* y_true = (const int*)d_in[1];
    int n = in_sizes[1];  // N; y_pred has 2N floats
    float* out = (float*)d_out;

    int gx = (n + NT - 1) / NT;           // row blocks
    int nsplit = (n + MAXLEN - 1) / MAXLEN;  // column slices (16 for N=16384)
    int len = (n + nsplit - 1) / nsplit;
    int nb = gx * nsplit;

    float* partials = (float*)d_ws;  // nb floats; plain stores overwrite poison

    dim3 grid(gx, nsplit);
    fused_pair_kernel<<<grid, NT, 0, stream>>>(y_pred, y_true, n, len, partials);
    reduce_kernel<<<1, NT, 0, stream>>>(partials, nb, out);
}